// Round 1
// 212.538 us; speedup vs baseline: 1.0125x; 1.0125x over previous
//
#include <hip/hip_runtime.h>

// TinyMLP (2 -> 32 -> 32 -> 1, sigmoid) analytic input-gradient, fused, MFMA-based.
// TRANSPOSED dataflow: batch index stays on lane&15 (the MFMA column) through the
// whole tile; all MFMAs are operand-swapped (weights = A-operand, wave-invariant).
//   MFMA#0 (x2): -log2e*Z1^T = aW1 @ Y^T      (y hi/lo bf16 split, b1 in K-slots 6,7)
//   MFMA#1 (x2): -log2e*Z2^T = bW2s @ H1^T    (acc init = -log2e*b2, exp2-ready)
//   MFMA#2 (x2): dH1^T = (W2*W3) @ dZ2^T      (W3 folded into weights at init)
//   MFMA#3 (x1): dY^T  = W1 @ dZ1^T           (g1,g2 land in accY[0],accY[1], lanes 0-15)
// Every C-layout -> B-frag pivot = 2x ds_write_b64 + 1x ds_read_b128, conflict-free.
// Transcendentals minimized: 16 exp2 + 4 rcp per tile (batched reciprocal, groups of 4).
//
// Layouts (16x16x32 bf16, verified m89/m91/m120):
//   A-frag: lane holds A[m=lane&15][k=(lane>>4)*8+j]
//   B-frag: lane holds B[k=(lane>>4)*8+j][n=lane&15]
//   C/D:    lane holds D[row=(lane>>4)*4+r][col=lane&15]

#define H 32
#define NLOG2E (-1.4426950408889634f)

typedef __attribute__((ext_vector_type(8))) short bf16x8;
typedef __attribute__((ext_vector_type(4))) float f32x4;
typedef __attribute__((ext_vector_type(2))) float f32x2;
typedef __attribute__((ext_vector_type(2))) __bf16 bfx2;

#define MFMA16 __builtin_amdgcn_mfma_f32_16x16x32_bf16

__device__ __forceinline__ int cvt_pk_bf16(float a, float b) {
    f32x2 f; f[0] = a; f[1] = b;
    bfx2 r = __builtin_convertvector(f, bfx2);   // v_cvt_pk_bf16_f32 (RNE)
    return __builtin_bit_cast(int, r);
}
__device__ __forceinline__ unsigned f2bf(float f) {          // RNE bf16 bits
    return (unsigned)cvt_pk_bf16(f, 0.f) & 0xFFFFu;
}
__device__ __forceinline__ float bf2f(unsigned s) {          // bf16 bits -> float
    unsigned u = s << 16; return __builtin_bit_cast(float, u);
}
__device__ __forceinline__ float pklo(int p) {               // low bf16 of packed pair
    unsigned u = (unsigned)p << 16; return __builtin_bit_cast(float, u);
}
__device__ __forceinline__ float pkhi(int p) {               // high bf16 of packed pair
    unsigned u = (unsigned)p & 0xFFFF0000u; return __builtin_bit_cast(float, u);
}

// Batched reciprocal: one v_rcp_f32 for four positive values (a_i = 1+e, e in (0,256]:
// product <= ~3.3e8, no overflow; error ~few ulp, far below bf16 rounding).
__device__ __forceinline__ f32x4 rcp4(const f32x4 a) {
    float m01 = a[0] * a[1], m23 = a[2] * a[3];
    float r   = __builtin_amdgcn_rcpf(m01 * m23);
    float r01 = r * m23, r23 = r * m01;
    f32x4 s; s[0] = a[1] * r01; s[1] = a[0] * r01; s[2] = a[3] * r23; s[3] = a[2] * r23;
    return s;
}

__global__ __launch_bounds__(256, 8) void tinymlp_mfma_kernel(
    const float* __restrict__ x1, const float* __restrict__ x2,
    const float* __restrict__ y1, const float* __restrict__ y2,
    const float* __restrict__ W1, const float* __restrict__ b1,
    const float* __restrict__ W2, const float* __restrict__ b2,
    const float* __restrict__ W3,
    float4* __restrict__ out, int ntiles)
{
    // 4 waves x 1024 shorts (two 512-short regions per wave: R0 @0, R1 @512)
    __shared__ unsigned short lds0[4096];

    const int tid  = threadIdx.x;
    const int w    = tid >> 6;
    const int lane = tid & 63;
    const int m    = lane & 15;
    const int q    = lane >> 4;
    const int kb   = q * 8;

    // ---- wave-invariant weight fragments (all as MFMA A-operands) ----
    bf16x8 bW2s_0, bW2s_1, bW2T3_0, bW2T3_1, bW1r;
    #pragma unroll
    for (int j = 0; j < 8; ++j) {
        // A[h2][h1] = -log2e*W2[h1][h2]  (forward, exp2-ready scale folded)
        bW2s_0[j] = (short)f2bf(NLOG2E * W2[(kb + j) * H + m]);
        bW2s_1[j] = (short)f2bf(NLOG2E * W2[(kb + j) * H + m + 16]);
        // A[h1][h2] = W2[h1][h2]*W3[h2]  (backward, W3 pre-folded)
        const float w3 = W3[kb + j];
        bW2T3_0[j] = (short)f2bf(W2[m * H + kb + j] * w3);
        bW2T3_1[j] = (short)f2bf(W2[(m + 16) * H + kb + j] * w3);
        // A[c][h1] = W1[c][h1], rows >=2 are zero (dY^T)
        bW1r[j] = (m < 2) ? (short)f2bf(W1[m * H + kb + j]) : (short)0;
    }

    // layer-1 A-frags: hi/lo bf16 split of (-log2e*W1), b1 exact via K-slots 6,7.
    // K slots: 0,1 = whi (x yhi); 2,3 = wlo (x yhi); 4,5 = whi (x ylo); 6,7 = b1 hi/lo (x 1).
    union { int i[4]; bf16x8 v; } uW1lo, uW1hi;
    uW1lo.i[0] = uW1lo.i[1] = uW1lo.i[2] = uW1lo.i[3] = 0;
    uW1hi.i[0] = uW1hi.i[1] = uW1hi.i[2] = uW1hi.i[3] = 0;
    if (q == 0) {
        #pragma unroll
        for (int half = 0; half < 2; ++half) {
            const int h = m + 16 * half;
            const float wa = NLOG2E * W1[h];
            const float wb = NLOG2E * W1[H + h];
            const float bv = NLOG2E * b1[h];
            const unsigned ah = f2bf(wa), bh = f2bf(wb);
            const unsigned al = f2bf(wa - bf2f(ah)), bl = f2bf(wb - bf2f(bh));
            const unsigned ch = f2bf(bv);
            const unsigned cl = f2bf(bv - bf2f(ch));
            int i0 = (int)(ah | (bh << 16));
            int i1 = (int)(al | (bl << 16));
            int i3 = (int)(ch | (cl << 16));
            if (half == 0) { uW1lo.i[0] = i0; uW1lo.i[1] = i1; uW1lo.i[2] = i0; uW1lo.i[3] = i3; }
            else           { uW1hi.i[0] = i0; uW1hi.i[1] = i1; uW1hi.i[2] = i0; uW1hi.i[3] = i3; }
        }
    }

    // acc init for MFMA#1: -log2e*b2 at rows h2 = 4q+r (+16)
    f32x4 b2C0, b2C1;
    {
        const float4 t0 = ((const float4*)b2)[q];
        const float4 t1 = ((const float4*)b2)[q + 4];
        b2C0[0] = NLOG2E * t0.x; b2C0[1] = NLOG2E * t0.y; b2C0[2] = NLOG2E * t0.z; b2C0[3] = NLOG2E * t0.w;
        b2C1[0] = NLOG2E * t1.x; b2C1[1] = NLOG2E * t1.y; b2C1[2] = NLOG2E * t1.z; b2C1[3] = NLOG2E * t1.w;
    }

    // ---- LDS scatter addressing: value (batch=b, k) lives at short index
    //      (k>>3)*128 + b*8 + (k&7).  Lane (q,m) writes k = 4q+r (lo) and 16+4q+r (hi)
    //      as one ds_write_b64 each; reader lane reads 8 contiguous shorts = B-frag.
    unsigned short*       wp = &lds0[w * 1024 + (q >> 1) * 128 + m * 8 + (q & 1) * 4];
    const unsigned short* rp = &lds0[w * 1024 + lane * 8];

    const int gwave  = (blockIdx.x * blockDim.x + tid) >> 6;
    const int nwaves = (gridDim.x * blockDim.x) >> 6;
    unsigned idx = (unsigned)gwave * 16 + (unsigned)m;   // element index (loads + store)
    const unsigned step = (unsigned)nwaves * 16;

    for (int tile = gwave; tile < ntiles; tile += nwaves) {
        const float y1v = y1[idx];
        const float y2v = y2[idx];
        float xv1 = 0.f, xv2 = 0.f;
        if (lane < 16) { xv1 = x1[idx]; xv2 = x2[idx]; }   // early, latency-hidden

        // ---- B-frag for layer 1: y hi/lo split (fp32-equivalent z1) ----
        const int pkHI = cvt_pk_bf16(y1v, y2v);
        const float l1 = y1v - pklo(pkHI);
        const float l2 = y2v - pkhi(pkHI);
        const int pkLO = cvt_pk_bf16(l1, l2);
        union { int i[4]; bf16x8 v; } uY;
        uY.i[0] = pkHI; uY.i[1] = pkHI; uY.i[2] = pkLO; uY.i[3] = 0x3F803F80;  // (1.0,1.0)

        const f32x4 zf = {0.f, 0.f, 0.f, 0.f};

        // ---- MFMA#0: -log2e*z1^T (rows h1, cols batch) ----
        f32x4 zL = MFMA16(uW1lo.v, uY.v, zf, 0, 0, 0);
        f32x4 zH = MFMA16(uW1hi.v, uY.v, zf, 0, 0, 0);

        // ---- sigmoid layer 1: s = 1/(1+2^zarg), one rcp per 4 ----
        f32x4 aL, aH;
        #pragma unroll
        for (int r = 0; r < 4; ++r) {
            aL[r] = __builtin_amdgcn_exp2f(zL[r]);
            aH[r] = __builtin_amdgcn_exp2f(zH[r]);
        }
        aL += 1.0f; aH += 1.0f;
        const f32x4 sL = rcp4(aL);
        const f32x4 sH = rcp4(aH);
        const int P0 = cvt_pk_bf16(sL[0], sL[1]);
        const int P1 = cvt_pk_bf16(sL[2], sL[3]);
        const int P2 = cvt_pk_bf16(sH[0], sH[1]);
        const int P3 = cvt_pk_bf16(sH[2], sH[3]);

        // ---- pivot h1: C-layout -> B-frag via R0 ----
        int2 wv0; wv0.x = P0; wv0.y = P1;
        int2 wv1; wv1.x = P2; wv1.y = P3;
        *(int2*)wp         = wv0;
        *(int2*)(wp + 256) = wv1;
        __builtin_amdgcn_wave_barrier();
        const bf16x8 uaH = *(const bf16x8*)rp;

        // ---- MFMA#1: -log2e*z2^T, acc init -log2e*b2 ----
        f32x4 zzL = MFMA16(bW2s_0, uaH, b2C0, 0, 0, 0);
        f32x4 zzH = MFMA16(bW2s_1, uaH, b2C1, 0, 0, 0);

        // ---- dz2 = s2*(1-s2) (W3 folded into bW2T3) ----
        f32x4 cL, cH;
        #pragma unroll
        for (int r = 0; r < 4; ++r) {
            cL[r] = __builtin_amdgcn_exp2f(zzL[r]);
            cH[r] = __builtin_amdgcn_exp2f(zzH[r]);
        }
        cL += 1.0f; cH += 1.0f;
        const f32x4 s2L = rcp4(cL);
        const f32x4 s2H = rcp4(cH);
        f32x2 d0; d0[0] = s2L[0]; d0[1] = s2L[1]; d0 = __builtin_elementwise_fma(-d0, d0, d0);
        f32x2 d1; d1[0] = s2L[2]; d1[1] = s2L[3]; d1 = __builtin_elementwise_fma(-d1, d1, d1);
        f32x2 d2; d2[0] = s2H[0]; d2[1] = s2H[1]; d2 = __builtin_elementwise_fma(-d2, d2, d2);
        f32x2 d3; d3[0] = s2H[2]; d3[1] = s2H[3]; d3 = __builtin_elementwise_fma(-d3, d3, d3);

        // ---- pivot dz2: C-layout -> B-frag via R1 ----
        int2 qv0; qv0.x = cvt_pk_bf16(d0[0], d0[1]); qv0.y = cvt_pk_bf16(d1[0], d1[1]);
        int2 qv1; qv1.x = cvt_pk_bf16(d2[0], d2[1]); qv1.y = cvt_pk_bf16(d3[0], d3[1]);
        *(int2*)(wp + 512) = qv0;
        *(int2*)(wp + 768) = qv1;
        __builtin_amdgcn_wave_barrier();
        const bf16x8 aD = *(const bf16x8*)(rp + 512);

        // ---- MFMA#2: dH1^T = (W2*W3) @ dZ2^T ----
        f32x4 dLo = MFMA16(bW2T3_0, aD, zf, 0, 0, 0);
        f32x4 dHi = MFMA16(bW2T3_1, aD, zf, 0, 0, 0);

        // ---- dz1 = dH1^T * h1d  (h1d recomputed from packed bf16 s, same C rows) ----
        f32x2 sv, gg;
        sv[0] = pklo(P0); sv[1] = pkhi(P0);
        f32x2 h0 = __builtin_elementwise_fma(-sv, sv, sv);
        gg[0] = dLo[0]; gg[1] = dLo[1]; gg *= h0;
        const int G0 = cvt_pk_bf16(gg[0], gg[1]);
        sv[0] = pklo(P1); sv[1] = pkhi(P1);
        h0 = __builtin_elementwise_fma(-sv, sv, sv);
        gg[0] = dLo[2]; gg[1] = dLo[3]; gg *= h0;
        const int G1 = cvt_pk_bf16(gg[0], gg[1]);
        sv[0] = pklo(P2); sv[1] = pkhi(P2);
        h0 = __builtin_elementwise_fma(-sv, sv, sv);
        gg[0] = dHi[0]; gg[1] = dHi[1]; gg *= h0;
        const int G2 = cvt_pk_bf16(gg[0], gg[1]);
        sv[0] = pklo(P3); sv[1] = pkhi(P3);
        h0 = __builtin_elementwise_fma(-sv, sv, sv);
        gg[0] = dHi[2]; gg[1] = dHi[3]; gg *= h0;
        const int G3 = cvt_pk_bf16(gg[0], gg[1]);

        // ---- pivot dz1: C-layout -> B-frag via R0 (reuse; same-wave DS is in-order) ----
        int2 gv0; gv0.x = G0; gv0.y = G1;
        int2 gv1; gv1.x = G2; gv1.y = G3;
        *(int2*)wp         = gv0;
        *(int2*)(wp + 256) = gv1;
        __builtin_amdgcn_wave_barrier();
        const bf16x8 uaG = *(const bf16x8*)rp;

        // ---- MFMA#3: dY^T = W1 @ dZ1^T -> lanes 0-15 hold g1=accY[0], g2=accY[1] ----
        f32x4 accY = MFMA16(bW1r, uaG, zf, 0, 0, 0);

        if (lane < 16) {
            float4 o;
            o.x = xv1 + accY[0];
            o.y = xv2 + accY[1];
            o.z = y1v;
            o.w = y2v;
            out[idx] = o;
        }
        __builtin_amdgcn_wave_barrier();   // keep next tile's LDS writes behind reads
        idx += step;
    }
}

extern "C" void kernel_launch(void* const* d_in, const int* in_sizes, int n_in,
                              void* d_out, int out_size, void* d_ws, size_t ws_size,
                              hipStream_t stream) {
    const float* x1 = (const float*)d_in[0];
    const float* x2 = (const float*)d_in[1];
    const float* y1 = (const float*)d_in[2];
    const float* y2 = (const float*)d_in[3];
    const float* W1 = (const float*)d_in[4];
    const float* b1 = (const float*)d_in[5];
    const float* W2 = (const float*)d_in[6];
    const float* b2 = (const float*)d_in[7];
    const float* W3 = (const float*)d_in[8];
    // d_in[9] = b3: drops out of the input-gradient — unused.

    const int n = in_sizes[0];
    const int ntiles = n / 16;       // B = 4194304 -> 262144 tiles
    const int block = 256;           // 4 waves
    const int grid = 2048;           // 8192 waves, grid-stride: 32 tiles/wave
    tinymlp_mfma_kernel<<<grid, block, 0, stream>>>(
        x1, x2, y1, y2, W1, b1, W2, b2, W3, (float4*)d_out, ntiles);
}